// Round 1
// baseline (667.651 us; speedup 1.0000x reference)
//
#include <hip/hip_runtime.h>

#define POOL 14
#define NUM_ROIS 512
#define IMG_H 200
#define IMG_W 200
#define IMG_C 1024

// One block (256 threads) per output cell (roi, py, px).
// Each thread handles 4 channels via float4: 256 * 4 = 1024 = C.
__global__ __launch_bounds__(256) void roi_bilinear_kernel(
    const float* __restrict__ img,   // (200,200,1024)
    const int*   __restrict__ rois,  // (512,4) as x,y,w,h
    float*       __restrict__ out)   // (512,14,14,1024)
{
    const int cell = blockIdx.x;                 // 0 .. 512*196-1
    const int r    = cell / (POOL * POOL);
    const int pp   = cell - r * (POOL * POOL);
    const int py   = pp / POOL;
    const int px   = pp - py * POOL;

    const int bx = rois[r * 4 + 0];
    const int by = rois[r * 4 + 1];
    const int bw = rois[r * 4 + 2];
    const int bh = rois[r * 4 + 3];

    // Mirror jnp float32 semantics exactly:
    // sy = py * (h / 14.0f); y0 = floor(sy); wy = sy - y0; clip to [0, h-1]
    const float sy = (float)py * ((float)bh / (float)POOL);
    const float sx = (float)px * ((float)bw / (float)POOL);
    const int y0 = (int)floorf(sy);
    const int x0 = (int)floorf(sx);
    const float wy = sy - (float)y0;
    const float wx = sx - (float)x0;

    const int y0c = min(max(y0, 0), bh - 1);
    const int y1c = min(max(y0 + 1, 0), bh - 1);
    const int x0c = min(max(x0, 0), bw - 1);
    const int x1c = min(max(x0 + 1, 0), bw - 1);

    const int iy0 = by + y0c;
    const int iy1 = by + y1c;
    const int ix0 = bx + x0c;
    const int ix1 = bx + x1c;

    const int c = threadIdx.x * 4;

    const float4 g00 = *(const float4*)(img + ((size_t)iy0 * IMG_W + ix0) * IMG_C + c);
    const float4 g01 = *(const float4*)(img + ((size_t)iy0 * IMG_W + ix1) * IMG_C + c);
    const float4 g10 = *(const float4*)(img + ((size_t)iy1 * IMG_W + ix0) * IMG_C + c);
    const float4 g11 = *(const float4*)(img + ((size_t)iy1 * IMG_W + ix1) * IMG_C + c);

    float4 res;
    {
        float top, bot;
        top = g00.x + (g01.x - g00.x) * wx;
        bot = g10.x + (g11.x - g10.x) * wx;
        res.x = top + (bot - top) * wy;
        top = g00.y + (g01.y - g00.y) * wx;
        bot = g10.y + (g11.y - g10.y) * wx;
        res.y = top + (bot - top) * wy;
        top = g00.z + (g01.z - g00.z) * wx;
        bot = g10.z + (g11.z - g10.z) * wx;
        res.z = top + (bot - top) * wy;
        top = g00.w + (g01.w - g00.w) * wx;
        bot = g10.w + (g11.w - g10.w) * wx;
        res.w = top + (bot - top) * wy;
    }

    *(float4*)(out + (size_t)cell * IMG_C + c) = res;
}

extern "C" void kernel_launch(void* const* d_in, const int* in_sizes, int n_in,
                              void* d_out, int out_size, void* d_ws, size_t ws_size,
                              hipStream_t stream) {
    const float* img  = (const float*)d_in[0];
    const int*   rois = (const int*)d_in[1];
    float*       out  = (float*)d_out;

    const int num_cells = NUM_ROIS * POOL * POOL;  // 100352
    roi_bilinear_kernel<<<num_cells, 256, 0, stream>>>(img, rois, out);
}

// Round 2
// 633.826 us; speedup vs baseline: 1.0534x; 1.0534x over previous
//
#include <hip/hip_runtime.h>

#define POOL 14
#define NUM_ROIS 512
#define IMG_H 200
#define IMG_W 200
#define IMG_C 1024
#define NUM_XCD 8

// One block (256 threads) per (roi, py) row: 14 cells, each thread owns 4
// channels (256*4 = 1024 = C). Rows iy0/iy1 are invariant across the row.
// Block index is swizzled so that all 14 rows (196 cells) of a given ROI land
// on the SAME XCD (hardware round-robins blockIdx % 8 -> XCD): this keeps the
// ROI's ~2 MB corner footprint inside one 4 MiB L2, capturing corner sharing
// between adjacent cells instead of re-fetching across non-coherent L2s.
__global__ __launch_bounds__(256) void roi_row_kernel(
    const float* __restrict__ img,   // (200,200,1024)
    const int*   __restrict__ rois,  // (512,4) x,y,w,h
    float*       __restrict__ out)   // (512,14,14,1024)
{
    const int b   = blockIdx.x;        // 0 .. 512*14-1 = 7167
    const int xcd = b & (NUM_XCD - 1); // which XCD this block lands on
    const int s   = b >> 3;            // 0 .. 895  (per-XCD sequence)
    const int roi_in = s / POOL;       // 0 .. 63
    const int py     = s - roi_in * POOL;
    const int r      = xcd * (NUM_ROIS / NUM_XCD) + roi_in;  // ROI -> one XCD

    const int4 box = ((const int4*)rois)[r];
    const int bx = box.x, by = box.y, bw = box.z, bh = box.w;

    // jnp f32 semantics: s = arange(POOL) * (dim / 14.0f)
    const float stepy = (float)bh / (float)POOL;
    const float stepx = (float)bw / (float)POOL;

    const float sy = (float)py * stepy;
    const int   y0 = (int)floorf(sy);
    const float wy = sy - (float)y0;
    const int y0c = min(max(y0, 0), bh - 1);
    const int y1c = min(max(y0 + 1, 0), bh - 1);

    const float* __restrict__ row0 = img + (size_t)(by + y0c) * IMG_W * IMG_C;
    const float* __restrict__ row1 = img + (size_t)(by + y1c) * IMG_W * IMG_C;

    const int c = threadIdx.x * 4;
    float* __restrict__ orow =
        out + ((size_t)r * (POOL * POOL) + (size_t)py * POOL) * IMG_C + c;

#pragma unroll
    for (int px = 0; px < POOL; ++px) {
        const float sx = (float)px * stepx;
        const int   x0 = (int)floorf(sx);
        const float wx = sx - (float)x0;
        const int x0c = min(max(x0, 0), bw - 1);
        const int x1c = min(max(x0 + 1, 0), bw - 1);
        const int ix0 = bx + x0c;
        const int ix1 = bx + x1c;

        const float4 g00 = *(const float4*)(row0 + (size_t)ix0 * IMG_C + c);
        const float4 g01 = *(const float4*)(row0 + (size_t)ix1 * IMG_C + c);
        const float4 g10 = *(const float4*)(row1 + (size_t)ix0 * IMG_C + c);
        const float4 g11 = *(const float4*)(row1 + (size_t)ix1 * IMG_C + c);

        float4 res;
        float top, bot;
        top = g00.x + (g01.x - g00.x) * wx;
        bot = g10.x + (g11.x - g10.x) * wx;
        res.x = top + (bot - top) * wy;
        top = g00.y + (g01.y - g00.y) * wx;
        bot = g10.y + (g11.y - g10.y) * wx;
        res.y = top + (bot - top) * wy;
        top = g00.z + (g01.z - g00.z) * wx;
        bot = g10.z + (g11.z - g10.z) * wx;
        res.z = top + (bot - top) * wy;
        top = g00.w + (g01.w - g00.w) * wx;
        bot = g10.w + (g11.w - g10.w) * wx;
        res.w = top + (bot - top) * wy;

        *(float4*)(orow + (size_t)px * IMG_C) = res;
    }
}

extern "C" void kernel_launch(void* const* d_in, const int* in_sizes, int n_in,
                              void* d_out, int out_size, void* d_ws, size_t ws_size,
                              hipStream_t stream) {
    const float* img  = (const float*)d_in[0];
    const int*   rois = (const int*)d_in[1];
    float*       out  = (float*)d_out;

    const int num_blocks = NUM_ROIS * POOL;  // 7168
    roi_row_kernel<<<num_blocks, 256, 0, stream>>>(img, rois, out);
}